// Round 5
// baseline (25.456 us; speedup 1.0000x reference)
//
#include <hip/hip_runtime.h>
#include <math.h>

#define B_SZ 2
#define T_SZ 512
#define D_SZ 64
#define ELEMS 4096            // D*D

// scan kernel geometry: 512 blocks = 128 rows x 4 col-quarters.
// block = 512 threads = 32 chunks x 16 cols; each thread scans 16 timesteps.
#define NCH  32               // chunks per row
#define CLEN 16               // timesteps per chunk (NCH*CLEN == T_SZ)
#define NCOL 16               // columns per block

// ws layout: decay_t [B][D][T] floats at 0 (256 KB); stats float2[B*T] at 256K (8 KB)
#define DECAY_BYTES ((size_t)B_SZ * D_SZ * T_SZ * 4)
#define STATS_OFF   DECAY_BYTES

// Kernel 1: per-(b,t) LayerNorm stats over D*D + row-dot with dt_w, softplus,
// decay = exp(softplus(dot+dt_b) * -exp(log_A[r])). Writes decay (transposed
// [b][r][t]) and stats (mu, rs). Does NOT write xn.
__global__ __launch_bounds__(256) void ln_dt_kernel(
    const float* __restrict__ x, const float* __restrict__ log_A,
    const float* __restrict__ dt_w, const float* __restrict__ dt_b,
    const float* __restrict__ ln_w, const float* __restrict__ ln_b,
    float* __restrict__ decay_t, float2* __restrict__ stats)
{
    const int bt  = blockIdx.x;            // 0..B*T-1
    const int tid = threadIdx.x;           // 0..255
    const size_t base = (size_t)bt * ELEMS;

    float4 v[4];
    float sum = 0.f, sumsq = 0.f;
    const float4* xv4 = reinterpret_cast<const float4*>(x + base);
#pragma unroll
    for (int k = 0; k < 4; ++k) {
        v[k] = xv4[tid + 256 * k];
        sum   += v[k].x + v[k].y + v[k].z + v[k].w;
        sumsq += v[k].x * v[k].x + v[k].y * v[k].y + v[k].z * v[k].z + v[k].w * v[k].w;
    }

    __shared__ float red0[4], red1[4];
#pragma unroll
    for (int off = 32; off; off >>= 1) {
        sum   += __shfl_down(sum, off);
        sumsq += __shfl_down(sumsq, off);
    }
    const int wave = tid >> 6;
    if ((tid & 63) == 0) { red0[wave] = sum; red1[wave] = sumsq; }
    __syncthreads();
    sum   = red0[0] + red0[1] + red0[2] + red0[3];
    sumsq = red1[0] + red1[1] + red1[2] + red1[3];

    const float mu = sum * (1.f / ELEMS);
    const float var = sumsq * (1.f / ELEMS) - mu * mu;
    const float rs = rsqrtf(var + 1e-5f);

    const float4* w4p = reinterpret_cast<const float4*>(ln_w);
    const float4* b4p = reinterpret_cast<const float4*>(ln_b);
    const float4* dw4 = reinterpret_cast<const float4*>(dt_w);
    float dot[4] = {0.f, 0.f, 0.f, 0.f};
#pragma unroll
    for (int k = 0; k < 4; ++k) {
        const int f = tid + 256 * k;
        float4 w4 = w4p[f];
        float4 b4 = b4p[f];
        float4 xn;
        xn.x = (v[k].x - mu) * rs * w4.x + b4.x;
        xn.y = (v[k].y - mu) * rs * w4.y + b4.y;
        xn.z = (v[k].z - mu) * rs * w4.z + b4.z;
        xn.w = (v[k].w - mu) * rs * w4.w + b4.w;
        float4 wv = dw4[f & 15];
        dot[k] += xn.x * wv.x + xn.y * wv.y + xn.z * wv.z + xn.w * wv.w;
    }

#pragma unroll
    for (int m = 1; m <= 8; m <<= 1) {
#pragma unroll
        for (int k = 0; k < 4; ++k) dot[k] += __shfl_xor(dot[k], m);
    }

    if (tid == 0) stats[bt] = make_float2(mu, rs);

    if ((tid & 15) == 0) {
        const int m = tid >> 4;
        const float db = dt_b[0];
        const int b = bt >> 9;           // bt / T_SZ
        const int t = bt & (T_SZ - 1);
#pragma unroll
        for (int k = 0; k < 4; ++k) {
            const int r = m + 16 * k;
            const float z = dot[k] + db;
            const float dt = (z > 20.f) ? z : log1pf(expf(z));
            const float A = -expf(log_A[r]);
            decay_t[((size_t)(b * D_SZ + r)) * T_SZ + t] = expf(dt * A);
        }
    }
}

// Kernel 2: block = (row, col-quarter). 512 blocks x 512 threads (full chip).
// thread = (chunk k, col): scans CLEN=16 timesteps of 1 column in registers,
// LN applied on the fly from stats. Cross-chunk carry via LDS fold.
__global__ __launch_bounds__(512, 4) void scan_fused_kernel(
    const float* __restrict__ x, const float2* __restrict__ stats,
    const float* __restrict__ decay_t,
    const float* __restrict__ ln_w, const float* __restrict__ ln_b,
    float* __restrict__ out)
{
    const int tid = threadIdx.x;
    const int col = tid & (NCOL - 1);     // 0..15
    const int k   = tid >> 4;             // chunk 0..31
    const int row = blockIdx.x >> 2;      // 0..127
    const int cq  = blockIdx.x & 3;       // column quarter
    const int b = row >> 6;
    const int r = row & 63;
    const int c = cq * NCOL + col;        // column 0..63

    __shared__ float  sd[T_SZ];           // decay for this row, all t
    __shared__ float2 sst[T_SZ];          // (mu, rs) per t
    __shared__ float  sS[NCH][NCOL];      // local-scan tails
    __shared__ float  sP[NCH];            // per-chunk decay products

    if (tid < T_SZ) {
        sd[tid]  = decay_t[(size_t)row * T_SZ + tid];
        sst[tid] = stats[(size_t)b * T_SZ + tid];
    }
    const float wr = ln_w[r * D_SZ + c];
    const float br = ln_b[r * D_SZ + c];
    __syncthreads();

    const int t0 = k * CLEN;
    const float* xp = x + ((size_t)(b * T_SZ + t0) * D_SZ + r) * D_SZ + c;

    // load + normalize + local inclusive scan
    float v[CLEN];
    float S = 0.f;
#pragma unroll
    for (int i = 0; i < CLEN; ++i) {
        const float  xv = xp[(size_t)i * ELEMS];
        const float2 st = sst[t0 + i];
        const float  xn = fmaf((xv - st.x) * st.y, wr, br);
        S = fmaf(S, sd[t0 + i], xn);
        v[i] = S;
    }

    if (col == 0) {
        float P = 1.f;
#pragma unroll
        for (int i = 0; i < CLEN; ++i) P *= sd[t0 + i];
        sP[k] = P;
    }
    sS[k][col] = S;
    __syncthreads();

    // carry-in for chunk k: fold C = S_j + P_j*C over chunks j < k
    float Cin = 0.f;
    for (int j = 0; j < k; ++j)
        Cin = fmaf(sP[j], Cin, sS[j][col]);

    // apply carry and write: out_t = v_t + cumprod(d)_t * Cin
    float* op = out + ((size_t)(b * T_SZ + t0) * D_SZ + r) * D_SZ + c;
    float rp = 1.f;
#pragma unroll
    for (int i = 0; i < CLEN; ++i) {
        rp *= sd[t0 + i];
        op[(size_t)i * ELEMS] = fmaf(rp, Cin, v[i]);
    }
}

extern "C" void kernel_launch(void* const* d_in, const int* in_sizes, int n_in,
                              void* d_out, int out_size, void* d_ws, size_t ws_size,
                              hipStream_t stream) {
    const float* x     = (const float*)d_in[0];
    const float* log_A = (const float*)d_in[1];
    const float* dt_w  = (const float*)d_in[2];
    const float* dt_b  = (const float*)d_in[3];
    const float* ln_w  = (const float*)d_in[4];
    const float* ln_b  = (const float*)d_in[5];
    float* out     = (float*)d_out;
    float* decay_t = (float*)d_ws;
    float2* stats  = (float2*)((char*)d_ws + STATS_OFF);

    ln_dt_kernel<<<B_SZ * T_SZ, 256, 0, stream>>>(
        x, log_A, dt_w, dt_b, ln_w, ln_b, decay_t, stats);

    scan_fused_kernel<<<B_SZ * D_SZ * 4, 512, 0, stream>>>(
        x, stats, decay_t, ln_w, ln_b, out);
}